// Round 14
// baseline (106.932 us; speedup 1.0000x reference)
//
#include <hip/hip_runtime.h>

// HyperLayer, R14: R13 + nontemporal streaming hints.
// R13 post-mortem: vectorized gather gave -1.4us (partial confirm of the
// request-count theory). Remaining suspect, evidenced by R8's FETCH=37MB vs
// ~10MB of actual input stream: (a) L2 write-allocate fetches on recbuf's
// scattered partial-line 16B stores (~8-15MB hidden HBM reads), (b) x (4MB,
// hot) evicted from each XCD L2 by the 10MB ri/vals stream each call (~12MB
// x refetch seen in R1). Fix with `nt` cache hints, zero structural change:
//  - nontemporal record stores (write-around, no allocate-fetch)
//  - nontemporal record loads in phase2 (read-once, don't pollute)
//  - nontemporal ri/vals loads (streamed once; keep x resident)
// Everything else = R13/R9: fixed per-(bin,block) regions CAPR=40,
// cnt[blk][bin] coalesced, no global atomics, no memsets, 4-row bins,
// 2 dispatches, vectorized 8B x-gather, nt y stores.

#define IN_DIM   1024
#define OUT_COLS 1024
#define NBINS    256
#define NBLK     256
#define P1T      1024
#define P2T      1024
#define CAPR     40
#define TILE_F   4096
#define TILE_PAD (TILE_F + OUT_COLS + 8)

typedef float f2u __attribute__((ext_vector_type(2), aligned(4)));
typedef float f4n __attribute__((ext_vector_type(4)));   // native vecs: nontemporal builtins
typedef int   i4n __attribute__((ext_vector_type(4)));   // reject HIP_vector_type (R12)

__global__ __launch_bounds__(P1T) void hl_phase1(
    const float*  __restrict__ x,
    const f4n*    __restrict__ ri,
    const float*  __restrict__ vals,
    i4n*          __restrict__ recbuf,   // [NBINS*NBLK*CAPR], bin-major
    int*          __restrict__ cnt,      // [NBLK*NBINS], blk-major
    int n)
{
    __shared__ int cur[NBINS];
    const int tid = threadIdx.x;
    const int b   = blockIdx.x;

    if (tid < NBINS) cur[tid] = 0;
    __syncthreads();

    const int spb  = (n + NBLK - 1) / NBLK;        // 1954
    const int i_lo = b * spb;
    const int i_hi = (i_lo + spb < n) ? (i_lo + spb) : n;

    for (int i = i_lo + tid; i < i_hi; i += P1T) {
        f4n  r   = __builtin_nontemporal_load(ri + i);      // streamed once
        float val = __builtin_nontemporal_load(vals + i);

        float f0 = floorf(r.x), c0 = ceilf(r.x);
        float f1 = floorf(r.y), c1 = ceilf(r.y);
        float f2 = floorf(r.z), c2 = ceilf(r.z);
        float f3 = floorf(r.w), c3 = ceilf(r.w);
        float wf0 = 1.f - (r.x - f0), wc0 = 1.f - (c0 - r.x);
        float wf1 = 1.f - (r.y - f1), wc1 = 1.f - (c1 - r.y);
        float wf2 = 1.f - (r.z - f2), wc2 = 1.f - (c2 - r.z);
        float wf3 = 1.f - (r.w - f3);
        int if1=(int)f1, ic1=(int)c1;
        int if0=(int)f0, ic0=(int)c0;
        int if2=(int)f2, ic2=(int)c2, if3=(int)f3, ic3=(int)c3;

        // vectorized bilinear gather: one 8B load per row (cols if1, if1+1).
        // integral col (ic1==if1): both weights act on the low element.
        // x loads stay CACHED (hot, reused across waves & calls).
        float w1lo = (ic1 == if1) ? (wf1 + wc1) : wf1;
        float w1hi = (ic1 == if1) ? 0.f : wc1;
        const f2u* p0 = (const f2u*)(x + if0 * IN_DIM + if1);
        const f2u* p1 = (const f2u*)(x + ic0 * IN_DIM + if1);
        f2u row0 = *p0;
        f2u row1 = *p1;
        float s_ = wf0 * (w1lo * row0.x + w1hi * row0.y)
                 + wc0 * (w1lo * row1.x + w1hi * row1.y);
        s_ *= val;

        float w2a, w2b;
        if (ic2 == if2) { w2a = wf2 + wc2; w2b = 0.f; }
        else            { w2a = wf2;       w2b = wc2; }
        float w3enc = (ic3 == if3) ? 2.0f : wf3;   // decode: 2->(2,0), w->(w,1-w)

        int b0 = if2 >> 2, b1 = ic2 >> 2;
        i4n rec;
        rec.x = if2 * OUT_COLS + if3;
        rec.y = __float_as_int(w2a * s_);
        rec.z = __float_as_int((b1 == b0) ? w2b * s_ : 0.f);
        rec.w = __float_as_int(w3enc);
        int rank = atomicAdd(&cur[b0], 1);
        if (rank < CAPR)
            __builtin_nontemporal_store(rec,
                &recbuf[((size_t)b0 * NBLK + b) * CAPR + rank]);

        if (b1 != b0) {   // second row lands in next bin
            rec.x = ic2 * OUT_COLS + if3;
            rec.y = __float_as_int(w2b * s_);
            rec.z = __float_as_int(0.f);
            rank = atomicAdd(&cur[b1], 1);
            if (rank < CAPR)
                __builtin_nontemporal_store(rec,
                    &recbuf[((size_t)b1 * NBLK + b) * CAPR + rank]);
        }
    }
    __syncthreads();
    if (tid < NBINS) {
        int c = cur[tid];
        cnt[b * NBINS + tid] = (c < CAPR) ? c : CAPR;   // coalesced 1KB store
    }
}

__global__ __launch_bounds__(P2T) void hl_phase2(
    const i4n* __restrict__ recbuf,
    const int* __restrict__ cnt,
    float*     __restrict__ y)
{
    __shared__ __align__(16) float tile[TILE_PAD];
    const int bin = blockIdx.x;
    const int tid = threadIdx.x;
    for (int k = tid; k < TILE_PAD; k += P2T) tile[k] = 0.f;
    __syncthreads();

    // 4 threads per (bin,block) region: region = tid&255, sub-rank = tid>>8
    const int region = tid & (NBLK - 1);
    const int sub    = tid >> 8;
    const int c      = cnt[region * NBINS + bin];
    const i4n* rb    = recbuf + ((size_t)bin * NBLK + region) * CAPR;
    const int tilebase = bin * TILE_F;

    for (int r = sub; r < c; r += 4) {
        i4n rec = __builtin_nontemporal_load(rb + r);   // read-once stream
        int   idx = rec.x - tilebase;
        float u   = __int_as_float(rec.y);
        float v   = __int_as_float(rec.z);
        float w3e = __int_as_float(rec.w);
        float w3a, w3b;
        if (w3e == 2.0f) { w3a = 2.0f; w3b = 0.f; }
        else             { w3a = w3e;  w3b = 1.0f - w3e; }
        __hip_atomic_fetch_add(&tile[idx],     u * w3a, __ATOMIC_RELAXED, __HIP_MEMORY_SCOPE_WORKGROUP);
        __hip_atomic_fetch_add(&tile[idx + 1], u * w3b, __ATOMIC_RELAXED, __HIP_MEMORY_SCOPE_WORKGROUP);
        if (v != 0.f) {
            __hip_atomic_fetch_add(&tile[idx + 1024], v * w3a, __ATOMIC_RELAXED, __HIP_MEMORY_SCOPE_WORKGROUP);
            __hip_atomic_fetch_add(&tile[idx + 1025], v * w3b, __ATOMIC_RELAXED, __HIP_MEMORY_SCOPE_WORKGROUP);
        }
    }
    __syncthreads();

    // tiles partition y exactly: nontemporal coalesced stores (y written once)
    f4n* y4 = (f4n*)y + bin * (TILE_F / 4);
    const f4n* t4 = (const f4n*)tile;
    for (int k = tid; k < TILE_F / 4; k += P2T)
        __builtin_nontemporal_store(t4[k], &y4[k]);
}

// ---- fallback (ws too small): direct-atomic kernel ----
__global__ __launch_bounds__(256) void hl_direct(
    const float* __restrict__ x, const float4* __restrict__ ri,
    const float* __restrict__ vals, float* __restrict__ y, int n)
{
    int i = blockIdx.x * blockDim.x + threadIdx.x;
    if (i >= n) return;
    float4 r = ri[i];
    float val = vals[i];
    float f0 = floorf(r.x), c0 = ceilf(r.x);
    float f1 = floorf(r.y), c1 = ceilf(r.y);
    float f2 = floorf(r.z), c2 = ceilf(r.z);
    float f3 = floorf(r.w), c3 = ceilf(r.w);
    float wf0 = 1.f-(r.x-f0), wc0 = 1.f-(c0-r.x);
    float wf1 = 1.f-(r.y-f1), wc1 = 1.f-(c1-r.y);
    float wf2 = 1.f-(r.z-f2), wc2 = 1.f-(c2-r.z);
    float wf3 = 1.f-(r.w-f3), wc3 = 1.f-(c3-r.w);
    int if0=(int)f0, ic0=(int)c0, if1=(int)f1, ic1=(int)c1;
    int if2=(int)f2, ic2=(int)c2, if3=(int)f3, ic3=(int)c3;
    const float* xr0 = x + if0 * IN_DIM;
    const float* xr1 = x + ic0 * IN_DIM;
    float s = wf0*(wf1*xr0[if1]+wc1*xr0[ic1]) + wc0*(wf1*xr1[if1]+wc1*xr1[ic1]);
    s *= val;
    float* y2 = y + if2 * OUT_COLS;
    float* y3 = y + ic2 * OUT_COLS;
    unsafeAtomicAdd(y2 + if3, wf2*wf3*s);
    unsafeAtomicAdd(y2 + ic3, wf2*wc3*s);
    unsafeAtomicAdd(y3 + if3, wc2*wf3*s);
    unsafeAtomicAdd(y3 + ic3, wc2*wc3*s);
}

extern "C" void kernel_launch(void* const* d_in, const int* in_sizes, int n_in,
                              void* d_out, int out_size, void* d_ws, size_t ws_size,
                              hipStream_t stream) {
    const float*  x    = (const float*)d_in[0];
    const f4n*    ri   = (const f4n*)d_in[1];
    const float*  vals = (const float*)d_in[2];
    float*        y    = (float*)d_out;
    int n = in_sizes[2];  // N = 500000

    const size_t REC_BYTES = (size_t)NBINS * NBLK * CAPR * sizeof(i4n);  // ~42 MB
    const size_t REQ = (1 << 20) + REC_BYTES;

    if (ws_size >= REQ) {
        int* cnt    = (int*)d_ws;                        // fully rewritten each call
        i4n* recbuf = (i4n*)((char*)d_ws + (1 << 20));   // 1MB-aligned offset
        hl_phase1<<<NBLK, P1T, 0, stream>>>(x, ri, vals, recbuf, cnt, n);
        hl_phase2<<<NBINS, P2T, 0, stream>>>(recbuf, cnt, y);
    } else {
        (void)hipMemsetAsync(y, 0, (size_t)out_size * sizeof(float), stream);
        int grid = (n + 255) / 256;
        hl_direct<<<grid, 256, 0, stream>>>(x, (const float4*)ri, vals, y, n);
    }
}

// Round 15
// 91.771 us; speedup vs baseline: 1.1652x; 1.1652x over previous
//
#include <hip/hip_runtime.h>

// HyperLayer, R15 = R13 revert (best: 92.4us).
// R14 post-mortem: nontemporal hints on SCATTERED record stores/loads
// regressed +14.5us -- nt is write-through/around, so every 16B record store
// became an HBM partial-line transaction and phase2's record reads skipped
// L2. L2 write-back caching was exactly what made the record round-trip
// cheap. nt is kept ONLY on the coalesced full-line y store (part of R13's
// win). Final structure:
//  - phase1: 256 blocks x 1024thr; vectorized 8B x-gather (one
//    global_load_dwordx2 per row pair; if1<=1022 always so in-bounds;
//    integral col folds wc1 into low-element weight); fixed per-(bin,block)
//    record regions CAPR=40 (overflow P~1e-8); cnt[blk][bin] coalesced
//    store; no global atomics; no memsets.
//  - record (16B): {x=flat idx, y=u=w2a*s, z=v=w2b*s (same-bin row pair),
//    w=w3enc}; integral floor==ceil double-count folded into w2a /
//    w3enc==2.0; bin-straddling row pair -> 2nd record in next bin.
//  - phase2: bin=block; 4 threads per (bin,block) region; ds_add into 4-row
//    LDS tile (+1 row margin absorbs weight-0 edge adds); nt coalesced
//    float4 y writes. Tiles partition y exactly -> no y memset.
// Session scoreboard: R3 (scatter atomics -> LDS two-phase) was the only
// large lever (-60us kernel); R13 vectorized gather -1.4us; everything else
// (claim atomics, record layout/staging, occupancy, fusion, nt hints) was
// neutral or negative. R11 diagnostic: phases cost ~24us intrinsic
// (scattered-request latency + ~10us/dispatch ramp at this size) vs ~62us
// fixed harness poison/restore overhead.

#define IN_DIM   1024
#define OUT_COLS 1024
#define NBINS    256
#define NBLK     256
#define P1T      1024
#define P2T      1024
#define CAPR     40
#define TILE_F   4096
#define TILE_PAD (TILE_F + OUT_COLS + 8)

typedef float f2u __attribute__((ext_vector_type(2), aligned(4)));
typedef float f4n __attribute__((ext_vector_type(4)));   // native vec for nontemporal store

__global__ __launch_bounds__(P1T) void hl_phase1(
    const float*  __restrict__ x,
    const float4* __restrict__ ri,
    const float*  __restrict__ vals,
    int4*         __restrict__ recbuf,   // [NBINS*NBLK*CAPR], bin-major
    int*          __restrict__ cnt,      // [NBLK*NBINS], blk-major
    int n)
{
    __shared__ int cur[NBINS];
    const int tid = threadIdx.x;
    const int b   = blockIdx.x;

    if (tid < NBINS) cur[tid] = 0;
    __syncthreads();

    const int spb  = (n + NBLK - 1) / NBLK;        // 1954
    const int i_lo = b * spb;
    const int i_hi = (i_lo + spb < n) ? (i_lo + spb) : n;

    for (int i = i_lo + tid; i < i_hi; i += P1T) {
        float4 r  = ri[i];
        float val = vals[i];

        float f0 = floorf(r.x), c0 = ceilf(r.x);
        float f1 = floorf(r.y), c1 = ceilf(r.y);
        float f2 = floorf(r.z), c2 = ceilf(r.z);
        float f3 = floorf(r.w), c3 = ceilf(r.w);
        float wf0 = 1.f - (r.x - f0), wc0 = 1.f - (c0 - r.x);
        float wf1 = 1.f - (r.y - f1), wc1 = 1.f - (c1 - r.y);
        float wf2 = 1.f - (r.z - f2), wc2 = 1.f - (c2 - r.z);
        float wf3 = 1.f - (r.w - f3);
        int if1=(int)f1, ic1=(int)c1;
        int if0=(int)f0, ic0=(int)c0;
        int if2=(int)f2, ic2=(int)c2, if3=(int)f3, ic3=(int)c3;

        // vectorized bilinear gather: one 8B load per row (cols if1, if1+1).
        // integral col (ic1==if1): both weights act on the low element.
        float w1lo = (ic1 == if1) ? (wf1 + wc1) : wf1;
        float w1hi = (ic1 == if1) ? 0.f : wc1;
        const f2u* p0 = (const f2u*)(x + if0 * IN_DIM + if1);
        const f2u* p1 = (const f2u*)(x + ic0 * IN_DIM + if1);
        f2u row0 = *p0;
        f2u row1 = *p1;
        float s_ = wf0 * (w1lo * row0.x + w1hi * row0.y)
                 + wc0 * (w1lo * row1.x + w1hi * row1.y);
        s_ *= val;

        float w2a, w2b;
        if (ic2 == if2) { w2a = wf2 + wc2; w2b = 0.f; }
        else            { w2a = wf2;       w2b = wc2; }
        float w3enc = (ic3 == if3) ? 2.0f : wf3;   // decode: 2->(2,0), w->(w,1-w)

        int b0 = if2 >> 2, b1 = ic2 >> 2;
        int4 rec;
        rec.x = if2 * OUT_COLS + if3;
        rec.y = __float_as_int(w2a * s_);
        rec.z = __float_as_int((b1 == b0) ? w2b * s_ : 0.f);
        rec.w = __float_as_int(w3enc);
        int rank = atomicAdd(&cur[b0], 1);
        if (rank < CAPR)
            recbuf[((size_t)b0 * NBLK + b) * CAPR + rank] = rec;

        if (b1 != b0) {   // second row lands in next bin
            rec.x = ic2 * OUT_COLS + if3;
            rec.y = __float_as_int(w2b * s_);
            rec.z = __float_as_int(0.f);
            rank = atomicAdd(&cur[b1], 1);
            if (rank < CAPR)
                recbuf[((size_t)b1 * NBLK + b) * CAPR + rank] = rec;
        }
    }
    __syncthreads();
    if (tid < NBINS) {
        int c = cur[tid];
        cnt[b * NBINS + tid] = (c < CAPR) ? c : CAPR;   // coalesced 1KB store
    }
}

__global__ __launch_bounds__(P2T) void hl_phase2(
    const int4* __restrict__ recbuf,
    const int*  __restrict__ cnt,
    float*      __restrict__ y)
{
    __shared__ __align__(16) float tile[TILE_PAD];
    const int bin = blockIdx.x;
    const int tid = threadIdx.x;
    for (int k = tid; k < TILE_PAD; k += P2T) tile[k] = 0.f;
    __syncthreads();

    // 4 threads per (bin,block) region: region = tid&255, sub-rank = tid>>8
    const int region = tid & (NBLK - 1);
    const int sub    = tid >> 8;
    const int c      = cnt[region * NBINS + bin];
    const int4* rb   = recbuf + ((size_t)bin * NBLK + region) * CAPR;
    const int tilebase = bin * TILE_F;

    for (int r = sub; r < c; r += 4) {
        int4 rec = rb[r];
        int   idx = rec.x - tilebase;
        float u   = __int_as_float(rec.y);
        float v   = __int_as_float(rec.z);
        float w3e = __int_as_float(rec.w);
        float w3a, w3b;
        if (w3e == 2.0f) { w3a = 2.0f; w3b = 0.f; }
        else             { w3a = w3e;  w3b = 1.0f - w3e; }
        __hip_atomic_fetch_add(&tile[idx],     u * w3a, __ATOMIC_RELAXED, __HIP_MEMORY_SCOPE_WORKGROUP);
        __hip_atomic_fetch_add(&tile[idx + 1], u * w3b, __ATOMIC_RELAXED, __HIP_MEMORY_SCOPE_WORKGROUP);
        if (v != 0.f) {
            __hip_atomic_fetch_add(&tile[idx + 1024], v * w3a, __ATOMIC_RELAXED, __HIP_MEMORY_SCOPE_WORKGROUP);
            __hip_atomic_fetch_add(&tile[idx + 1025], v * w3b, __ATOMIC_RELAXED, __HIP_MEMORY_SCOPE_WORKGROUP);
        }
    }
    __syncthreads();

    // tiles partition y exactly: nontemporal coalesced stores (y written once)
    f4n* y4 = (f4n*)y + bin * (TILE_F / 4);
    const f4n* t4 = (const f4n*)tile;
    for (int k = tid; k < TILE_F / 4; k += P2T)
        __builtin_nontemporal_store(t4[k], &y4[k]);
}

// ---- fallback (ws too small): direct-atomic kernel ----
__global__ __launch_bounds__(256) void hl_direct(
    const float* __restrict__ x, const float4* __restrict__ ri,
    const float* __restrict__ vals, float* __restrict__ y, int n)
{
    int i = blockIdx.x * blockDim.x + threadIdx.x;
    if (i >= n) return;
    float4 r = ri[i];
    float val = vals[i];
    float f0 = floorf(r.x), c0 = ceilf(r.x);
    float f1 = floorf(r.y), c1 = ceilf(r.y);
    float f2 = floorf(r.z), c2 = ceilf(r.z);
    float f3 = floorf(r.w), c3 = ceilf(r.w);
    float wf0 = 1.f-(r.x-f0), wc0 = 1.f-(c0-r.x);
    float wf1 = 1.f-(r.y-f1), wc1 = 1.f-(c1-r.y);
    float wf2 = 1.f-(r.z-f2), wc2 = 1.f-(c2-r.z);
    float wf3 = 1.f-(r.w-f3), wc3 = 1.f-(c3-r.w);
    int if0=(int)f0, ic0=(int)c0, if1=(int)f1, ic1=(int)c1;
    int if2=(int)f2, ic2=(int)c2, if3=(int)f3, ic3=(int)c3;
    const float* xr0 = x + if0 * IN_DIM;
    const float* xr1 = x + ic0 * IN_DIM;
    float s = wf0*(wf1*xr0[if1]+wc1*xr0[ic1]) + wc0*(wf1*xr1[if1]+wc1*xr1[ic1]);
    s *= val;
    float* y2 = y + if2 * OUT_COLS;
    float* y3 = y + ic2 * OUT_COLS;
    unsafeAtomicAdd(y2 + if3, wf2*wf3*s);
    unsafeAtomicAdd(y2 + ic3, wf2*wc3*s);
    unsafeAtomicAdd(y3 + if3, wc2*wf3*s);
    unsafeAtomicAdd(y3 + ic3, wc2*wc3*s);
}

extern "C" void kernel_launch(void* const* d_in, const int* in_sizes, int n_in,
                              void* d_out, int out_size, void* d_ws, size_t ws_size,
                              hipStream_t stream) {
    const float*  x    = (const float*)d_in[0];
    const float4* ri   = (const float4*)d_in[1];
    const float*  vals = (const float*)d_in[2];
    float*        y    = (float*)d_out;
    int n = in_sizes[2];  // N = 500000

    const size_t REC_BYTES = (size_t)NBINS * NBLK * CAPR * sizeof(int4);  // ~42 MB
    const size_t REQ = (1 << 20) + REC_BYTES;

    if (ws_size >= REQ) {
        int*  cnt    = (int*)d_ws;                        // fully rewritten each call
        int4* recbuf = (int4*)((char*)d_ws + (1 << 20));  // 1MB-aligned offset
        hl_phase1<<<NBLK, P1T, 0, stream>>>(x, ri, vals, recbuf, cnt, n);
        hl_phase2<<<NBINS, P2T, 0, stream>>>(recbuf, cnt, y);
    } else {
        (void)hipMemsetAsync(y, 0, (size_t)out_size * sizeof(float), stream);
        int grid = (n + 255) / 256;
        hl_direct<<<grid, 256, 0, stream>>>(x, ri, vals, y, n);
    }
}